// Round 13
// baseline (153.001 us; speedup 1.0000x reference)
//
#include <hip/hip_runtime.h>
#include <math.h>

#define BB 4
#define LL 1024
#define EE 512
#define HH 8
#define DD 64
#define MAXREL 512

typedef unsigned short u16;
typedef __attribute__((ext_vector_type(8))) short bf16x8;
typedef __attribute__((ext_vector_type(4))) float f32x4;

__device__ __forceinline__ u16 f2bf(float f) {
    unsigned int u = __float_as_uint(f);
    unsigned int r = (u + 0x7FFFu + ((u >> 16) & 1u)) >> 16;
    return (u16)r;
}
__device__ __forceinline__ bf16x8 ldf8_bf(const float* p) {
    const float4 a = *(const float4*)(p);
    const float4 b = *(const float4*)(p + 4);
    bf16x8 r;
    r[0] = (short)f2bf(a.x); r[1] = (short)f2bf(a.y);
    r[2] = (short)f2bf(a.z); r[3] = (short)f2bf(a.w);
    r[4] = (short)f2bf(b.x); r[5] = (short)f2bf(b.y);
    r[6] = (short)f2bf(b.z); r[7] = (short)f2bf(b.w);
    return r;
}

#define MF(A, B, C) __builtin_amdgcn_mfma_f32_16x16x32_bf16((A), (B), (C), 0, 0, 0)
// exp(x/8) = exp2(x * log2(e)/8)
#define EXPSC 0.1803368801111244f

// ---------------- projection via MFMA ----------------
__global__ __launch_bounds__(256) void proj_mfma_kernel(
    const float* __restrict__ q_in, const float* __restrict__ k_in, const float* __restrict__ v_in,
    const float* __restrict__ Wq, const float* __restrict__ bq,
    const float* __restrict__ Wk, const float* __restrict__ bk,
    const float* __restrict__ Wv, const float* __restrict__ bv,
    u16* __restrict__ qb, u16* __restrict__ kb, u16* __restrict__ vtb)
{
    int bh = blockIdx.x; int b = bh >> 3; int h = bh & 7;
    int l0 = blockIdx.y * 64;
    int t = threadIdx.x; int w = t >> 6; int lane = t & 63;
    int lg = lane >> 4, lc = lane & 15;
    int lt = l0 + w * 16;

    bf16x8 wq[4][2], wk[4][2], wv[4][2];
    #pragma unroll
    for (int dt = 0; dt < 4; ++dt)
        #pragma unroll
        for (int kc = 0; kc < 2; ++kc) {
            int d = dt * 16 + lc, ko = kc * 32 + lg * 8;
            wq[dt][kc] = ldf8_bf(Wq + d * DD + ko);
            wk[dt][kc] = ldf8_bf(Wk + d * DD + ko);
            wv[dt][kc] = ldf8_bf(Wv + d * DD + ko);
        }
    size_t xrow = ((size_t)b * LL + lt + lc) * EE + h * DD;
    bf16x8 xq[2], xk[2], xv[2];
    #pragma unroll
    for (int kc = 0; kc < 2; ++kc) {
        int ko = kc * 32 + lg * 8;
        xq[kc] = ldf8_bf(q_in + xrow + ko);
        xk[kc] = ldf8_bf(k_in + xrow + ko);
        xv[kc] = ldf8_bf(v_in + xrow + ko);
    }

    f32x4 aq[4] = {}, ak[4] = {}, av[4] = {};
    #pragma unroll
    for (int dt = 0; dt < 4; ++dt) {
        aq[dt] = MF(wq[dt][0], xq[0], aq[dt]);
        aq[dt] = MF(wq[dt][1], xq[1], aq[dt]);
        ak[dt] = MF(wk[dt][0], xk[0], ak[dt]);
        ak[dt] = MF(wk[dt][1], xk[1], ak[dt]);
        av[dt] = MF(xv[0], wv[dt][0], av[dt]);
        av[dt] = MF(xv[1], wv[dt][1], av[dt]);
    }

    #pragma unroll
    for (int dt = 0; dt < 4; ++dt) {
        u16 tq[4], tk[4], tv[4];
        #pragma unroll
        for (int r = 0; r < 4; ++r) {
            int d = dt * 16 + lg * 4 + r;
            tq[r] = f2bf(aq[dt][r] + bq[d]);
            tk[r] = f2bf(ak[dt][r] + bk[d]);
            tv[r] = f2bf(av[dt][r] + bv[dt * 16 + lc]);
        }
        size_t o = ((size_t)bh * LL + lt + lc) * DD + dt * 16 + lg * 4;
        *(uint2*)&qb[o] = *(uint2*)tq;
        *(uint2*)&kb[o] = *(uint2*)tk;
        size_t ov = ((size_t)bh * DD + dt * 16 + lc) * LL + lt + lg * 4;
        *(uint2*)&vtb[ov] = *(uint2*)tv;
    }
}

// ---------------- prep: padded bf16 rel tables + bf16 Wfc ----------------
__global__ __launch_bounds__(256) void prep_kernel(
    const float* __restrict__ relk, const float* __restrict__ relv, const float* __restrict__ Wfc,
    u16* __restrict__ relk_pad, u16* __restrict__ relvt_pad, u16* __restrict__ wfcb)
{
    int idx = blockIdx.x * 256 + threadIdx.x;   // 1024 blocks -> 262144
    if (idx < 2048 * DD) {
        int r = idx >> 6, d = idx & 63;
        int j = r - 512; j = j < 0 ? 0 : (j > 2 * MAXREL ? 2 * MAXREL : j);
        relk_pad[idx] = f2bf(relk[j * DD + d]);
        int dd = idx >> 11, c = idx & 2047;
        int j2 = c - 512; j2 = j2 < 0 ? 0 : (j2 > 2 * MAXREL ? 2 * MAXREL : j2);
        relvt_pad[idx] = f2bf(relv[j2 * DD + dd]);
    }
    if (idx < EE * EE) wfcb[idx] = f2bf(Wfc[idx]);
}

// ---------------- fused attention: softmax-behind pipeline, rel-V direct-global ----------------
// grid (B*H, L/32), block 256 (4 waves). 2 barriers/chunk. Wave-local P.
// Iter c: scores+softmax(c+1) (Ks single-buffer), PV(c). rel-V B-frags: direct
// global loads (named regs, issued at iter top — slack = P reads + 10 MFMAs).
__global__ __launch_bounds__(256) void attn_mfma_kernel(
    const u16* __restrict__ qb, const u16* __restrict__ kb, const u16* __restrict__ vtb,
    const int* __restrict__ mask,
    const u16* __restrict__ relk_pad, const u16* __restrict__ relvt_pad,
    u16* __restrict__ attn_out)
{
    __shared__ __align__(16) char smem[33024];
    u16* Ks   = (u16*)(smem);             // [64][72] 9216 (single buffer)
    u16* Vts  = (u16*)(smem + 9216);      // [64][72] 9216
    float* lred = (float*)(smem + 32768); // [64]
    float* obuf = (float*)smem;           // epilogue reuse [32][68] f32 (8704 B)

    int bh = blockIdx.x, b = bh >> 3, h = bh & 7;
    int q0 = blockIdx.y * 32;
    int t = threadIdx.x, lane = t & 63, w = t >> 6;
    int rw = w & 1, cw = w >> 1;
    int rbase = rw * 16, c0a = cw * 32;
    int lg = lane >> 4, lc = lane & 15;
    int ub = c0a - rbase + 16;            // window base (0,16,32,48)
    size_t bhL = (size_t)bh * LL;
    const u16* kb_bh = kb + bhL * DD;
    const u16* vt_bh = vtb + (size_t)bh * DD * LL;
    const int* mk_b = mask + b * LL;
    u16* Pw  = (u16*)(smem + 18432) + w * 640;   // [16][40] per wave (5120 B)
    u16* Pqw = (u16*)(smem + 23552) + w * 1152;  // [16][72] per wave (9216 B)

    // staging index precompute
    int sr0 = t >> 3, ss0 = (t & 7) * 8;
    int sr1 = sr0 + 32;
    const u16* rk_base = relk_pad + (size_t)(ub + lc) * DD + lg * 8;
    const u16* rv_base = relvt_pad + (size_t)lc * 2048 + ub + lg * 8;

    const u16* qrow = qb + (bhL + q0 + rbase + lc) * DD;
    bf16x8 qf0 = *(const bf16x8*)&qrow[lg * 8];
    bf16x8 qf1 = *(const bf16x8*)&qrow[32 + lg * 8];

    f32x4 s0, s1, g0, g1, g2;
    bf16x8 rk0, rk1, rk2, rk3, rk4, rk5;
    f32x4 oacc[4] = {};
    float lacc[4] = {0.f, 0.f, 0.f, 0.f};
    int delta0 = lc - lg * 4;

#define LOAD_RK(SB) do { \
    const u16* rkp_ = rk_base + (size_t)(SB) * DD; \
    rk0 = *(const bf16x8*)&rkp_[0]; \
    rk1 = *(const bf16x8*)&rkp_[32]; \
    rk2 = *(const bf16x8*)&rkp_[16 * DD]; \
    rk3 = *(const bf16x8*)&rkp_[16 * DD + 32]; \
    rk4 = *(const bf16x8*)&rkp_[32 * DD]; \
    rk5 = *(const bf16x8*)&rkp_[32 * DD + 32]; \
} while (0)

#define DO_SCORES() do { \
    const u16* kp0_ = Ks + (c0a + lc) * 72; \
    const u16* kp1_ = Ks + (c0a + 16 + lc) * 72; \
    s0 = (f32x4){0.f,0.f,0.f,0.f}; s1 = s0; g0 = s0; g1 = s0; g2 = s0; \
    __builtin_amdgcn_s_setprio(1); \
    s0 = MF(qf0, *(const bf16x8*)&kp0_[lg * 8], s0); \
    s0 = MF(qf1, *(const bf16x8*)&kp0_[32 + lg * 8], s0); \
    s1 = MF(qf0, *(const bf16x8*)&kp1_[lg * 8], s1); \
    s1 = MF(qf1, *(const bf16x8*)&kp1_[32 + lg * 8], s1); \
    g0 = MF(qf0, rk0, g0); g0 = MF(qf1, rk1, g0); \
    g1 = MF(qf0, rk2, g1); g1 = MF(qf1, rk3, g1); \
    g2 = MF(qf0, rk4, g2); g2 = MF(qf1, rk5, g2); \
    __builtin_amdgcn_s_setprio(0); \
} while (0)

#define DO_SOFTMAX(MB0, MB1) do { \
    _Pragma("unroll") \
    for (int r = 0; r < 4; ++r) { \
        int d_ = delta0 - r; \
        int src_ = (lane & 48) | (d_ & 15); \
        float a0_ = __shfl(g0[r], src_, 64); \
        float a1_ = __shfl(g1[r], src_, 64); \
        float a2_ = __shfl(g2[r], src_, 64); \
        float gv0_ = (d_ >= 0) ? a1_ : a0_; \
        float gv1_ = (d_ >= 0) ? a2_ : a1_; \
        float p0_ = exp2f((s0[r] + (MB0) + gv0_) * EXPSC); \
        float p1_ = exp2f((s1[r] + (MB1) + gv1_) * EXPSC); \
        unsigned pk_; \
        asm("v_cvt_pk_bf16_f32 %0, %1, %2" : "=v"(pk_) : "v"(p0_), "v"(p1_)); \
        u16 pb0_ = (u16)pk_, pb1_ = (u16)(pk_ >> 16); \
        lacc[r] += p0_ + p1_; \
        int row_ = lg * 4 + r; \
        Pw[row_ * 40 + lc] = pb0_; \
        Pw[row_ * 40 + 16 + lc] = pb1_; \
        Pqw[row_ * 72 + lc - row_ + 16] = pb0_; \
        Pqw[row_ * 72 + 32 + lc - row_] = pb1_; \
    } \
} while (0)

    // ---- prolog ----
    #pragma unroll
    for (int i = 0; i < 3; ++i) {
        int u = lane + i * 64;
        if (u < 144) *(uint4*)&Pqw[u * 8] = make_uint4(0, 0, 0, 0);
    }
    int sb0 = 992 - q0;
    *(uint4*)&Ks[sr0 * 72 + ss0] = *(const uint4*)&kb_bh[(size_t)sr0 * DD + ss0];
    *(uint4*)&Ks[sr1 * 72 + ss0] = *(const uint4*)&kb_bh[(size_t)sr1 * DD + ss0];
    *(uint4*)&Vts[sr0 * 72 + ss0] = *(const uint4*)&vt_bh[(size_t)sr0 * LL + ss0];
    *(uint4*)&Vts[sr1 * 72 + ss0] = *(const uint4*)&vt_bh[(size_t)sr1 * LL + ss0];
    LOAD_RK(sb0);
    float mbp0 = (mk_b[c0a + lc] != 0) ? 0.f : -1e20f;
    float mbp1 = (mk_b[c0a + 16 + lc] != 0) ? 0.f : -1e20f;
    __syncthreads();
    DO_SCORES();                          // chunk 0 (Ks = K(0))
    LOAD_RK(sb0 + 64);                    // rel-K(1)
    DO_SOFTMAX(mbp0, mbp1);               // P(0)
    {
        uint4 k1a = *(const uint4*)&kb_bh[(size_t)(64 + sr0) * DD + ss0];
        uint4 k1b = *(const uint4*)&kb_bh[(size_t)(64 + sr1) * DD + ss0];
        __syncthreads();                  // all done reading K(0)
        *(uint4*)&Ks[sr0 * 72 + ss0] = k1a;
        *(uint4*)&Ks[sr1 * 72 + ss0] = k1b;
        __syncthreads();                  // Ks = K(1)
    }

    // ---- main loop: iter c does scores/softmax(c+1) + PV(c) ----
    #pragma unroll 1
    for (int c = 0; c < 16; ++c) {
        int k0 = c * 64;
        int sb_ = k0 - q0 + 992;

        // rel-V B-frags for PV(c): direct global (named regs; long slack to use)
        const u16* rvp0 = rv_base + sb_;
        const u16* rvp1 = rvp0 + 16 * 2048;
        const u16* rvp2 = rvp0 + 32 * 2048;
        const u16* rvp3 = rvp0 + 48 * 2048;
        bf16x8 rv00 = *(const bf16x8*)(rvp0);
        bf16x8 rv01 = *(const bf16x8*)(rvp0 + 32);
        bf16x8 rv10 = *(const bf16x8*)(rvp1);
        bf16x8 rv11 = *(const bf16x8*)(rvp1 + 32);
        bf16x8 rv20 = *(const bf16x8*)(rvp2);
        bf16x8 rv21 = *(const bf16x8*)(rvp2 + 32);
        bf16x8 rv30 = *(const bf16x8*)(rvp3);
        bf16x8 rv31 = *(const bf16x8*)(rvp3 + 32);

        uint4 rK0, rK1, rV0, rV1;
        float mbn0 = 0.f, mbn1 = 0.f;
        if (c < 14) {
            rK0 = *(const uint4*)&kb_bh[(size_t)(k0 + 128 + sr0) * DD + ss0];
            rK1 = *(const uint4*)&kb_bh[(size_t)(k0 + 128 + sr1) * DD + ss0];
        }
        if (c < 15) {
            int k0n = k0 + 64;
            rV0 = *(const uint4*)&vt_bh[(size_t)sr0 * LL + k0n + ss0];
            rV1 = *(const uint4*)&vt_bh[(size_t)sr1 * LL + k0n + ss0];
            mbn0 = (mk_b[k0n + c0a + lc] != 0) ? 0.f : -1e20f;
            mbn1 = (mk_b[k0n + c0a + 16 + lc] != 0) ? 0.f : -1e20f;
        }

        // P(c) fragments (written last iteration / prolog; wave-local)
        bf16x8 pa  = *(const bf16x8*)&Pw[lc * 40 + lg * 8];
        bf16x8 pq0 = *(const bf16x8*)&Pqw[lc * 72 + lg * 8];
        bf16x8 pq1 = *(const bf16x8*)&Pqw[lc * 72 + 32 + lg * 8];

        if (c < 15) {
            DO_SCORES();                       // chunk c+1 (Ks = K(c+1))
            if (c < 14) LOAD_RK(sb_ + 128);    // rel-K(c+2)
        }

        // PV(c) — V from LDS, rel-V from registers
        __builtin_amdgcn_s_setprio(1);
        #pragma unroll
        for (int dt = 0; dt < 4; ++dt) {
            const u16* vp = &Vts[(dt * 16 + lc) * 72 + c0a];
            oacc[dt] = MF(pa, *(const bf16x8*)&vp[lg * 8], oacc[dt]);
        }
        oacc[0] = MF(pq0, rv00, oacc[0]); oacc[0] = MF(pq1, rv01, oacc[0]);
        oacc[1] = MF(pq0, rv10, oacc[1]); oacc[1] = MF(pq1, rv11, oacc[1]);
        oacc[2] = MF(pq0, rv20, oacc[2]); oacc[2] = MF(pq1, rv21, oacc[2]);
        oacc[3] = MF(pq0, rv30, oacc[3]); oacc[3] = MF(pq1, rv31, oacc[3]);
        __builtin_amdgcn_s_setprio(0);

        if (c < 15) {
            DO_SOFTMAX(mbn0, mbn1);            // P(c+1), overlaps PV drain
            __syncthreads();                   // all waves done reading chunk c tiles
            if (c < 14) {
                *(uint4*)&Ks[sr0 * 72 + ss0] = rK0;   // Ks <- K(c+2)
                *(uint4*)&Ks[sr1 * 72 + ss0] = rK1;
            }
            *(uint4*)&Vts[sr0 * 72 + ss0] = rV0;
            *(uint4*)&Vts[sr1 * 72 + ss0] = rV1;
            __syncthreads();                   // chunk c+1 tiles visible
        }
    }
#undef LOAD_RK
#undef DO_SCORES
#undef DO_SOFTMAX

    // ---- epilogue: row-sum + cw-pair combine ----
    #pragma unroll
    for (int m2 = 1; m2 <= 8; m2 <<= 1) {
        #pragma unroll
        for (int r = 0; r < 4; ++r) lacc[r] += __shfl_xor(lacc[r], m2);
    }
    __syncthreads();
    if (lc == 0) {
        #pragma unroll
        for (int r = 0; r < 4; ++r) lred[cw * 32 + rbase + lg * 4 + r] = lacc[r];
    }
    __syncthreads();
    if (cw == 1) {
        #pragma unroll
        for (int dt = 0; dt < 4; ++dt)
            #pragma unroll
            for (int r = 0; r < 4; ++r)
                obuf[(rbase + lg * 4 + r) * 68 + dt * 16 + lc] = oacc[dt][r];
    }
    __syncthreads();
    if (cw == 0) {
        float inv[4];
        #pragma unroll
        for (int r = 0; r < 4; ++r) {
            int row = rbase + lg * 4 + r;
            inv[r] = 1.0f / (lred[row] + lred[32 + row]);
        }
        #pragma unroll
        for (int dt = 0; dt < 4; ++dt) {
            #pragma unroll
            for (int r = 0; r < 4; ++r) {
                int row = rbase + lg * 4 + r;
                float v = (oacc[dt][r] + obuf[row * 68 + dt * 16 + lc]) * inv[r];
                attn_out[((size_t)b * LL + q0 + row) * EE + h * DD + dt * 16 + lc] = f2bf(v);
            }
        }
    }
}

// ---------------- final FC via MFMA: out = X @ Wfc.T + bfc ----------------
__global__ __launch_bounds__(256) void fc_mfma_kernel(
    const u16* __restrict__ Xb, const u16* __restrict__ Wb,
    const float* __restrict__ bfc, float* __restrict__ out)
{
    __shared__ u16 As[128][72];
    __shared__ u16 Bs[128][72];
    int m0 = blockIdx.x * 128, n0 = blockIdx.y * 128;
    int t = threadIdx.x, lane = t & 63, w = t >> 6;
    int rw = w & 1, cw = w >> 1;
    int lg = lane >> 4, lc = lane & 15;
    f32x4 acc[4][4] = {};

    for (int kt = 0; kt < EE; kt += 64) {
        __syncthreads();
        #pragma unroll
        for (int i = 0; i < 4; ++i) {
            int unit = i * 256 + t;
            int row = unit >> 3, s = unit & 7;
            *(uint4*)&As[row][s * 8] = *(const uint4*)&Xb[(size_t)(m0 + row) * EE + kt + s * 8];
            *(uint4*)&Bs[row][s * 8] = *(const uint4*)&Wb[(size_t)(n0 + row) * EE + kt + s * 8];
        }
        __syncthreads();
        #pragma unroll
        for (int kc = 0; kc < 2; ++kc) {
            bf16x8 af[4], bf[4];
            #pragma unroll
            for (int i = 0; i < 4; ++i) {
                af[i] = *(const bf16x8*)&As[rw * 64 + i * 16 + lc][kc * 32 + lg * 8];
                bf[i] = *(const bf16x8*)&Bs[cw * 64 + i * 16 + lc][kc * 32 + lg * 8];
            }
            #pragma unroll
            for (int mi = 0; mi < 4; ++mi)
                #pragma unroll
                for (int ni = 0; ni < 4; ++ni)
                    acc[mi][ni] = MF(af[mi], bf[ni], acc[mi][ni]);
        }
    }
    #pragma unroll
    for (int mi = 0; mi < 4; ++mi) {
        #pragma unroll
        for (int ni = 0; ni < 4; ++ni) {
            int n = n0 + cw * 64 + ni * 16 + lc;
            float bias = bfc[n];
            #pragma unroll
            for (int r = 0; r < 4; ++r) {
                int m = m0 + rw * 64 + mi * 16 + lg * 4 + r;
                out[(size_t)m * EE + n] = acc[mi][ni][r] + bias;
            }
        }
    }
}

extern "C" void kernel_launch(void* const* d_in, const int* in_sizes, int n_in,
                              void* d_out, int out_size, void* d_ws, size_t ws_size,
                              hipStream_t stream) {
    const float* query = (const float*)d_in[0];
    const float* key   = (const float*)d_in[1];
    const float* value = (const float*)d_in[2];
    const int*   mask  = (const int*)d_in[3];
    const float* Wq  = (const float*)d_in[4];
    const float* bq  = (const float*)d_in[5];
    const float* Wk  = (const float*)d_in[6];
    const float* bk  = (const float*)d_in[7];
    const float* Wv  = (const float*)d_in[8];
    const float* bv  = (const float*)d_in[9];
    const float* Wfc = (const float*)d_in[10];
    const float* bfc = (const float*)d_in[11];
    const float* relk = (const float*)d_in[12];
    const float* relv = (const float*)d_in[13];
    float* out = (float*)d_out;

    char* ws = (char*)d_ws;
    u16* qb        = (u16*)(ws);                            // 4 MB
    u16* kb        = (u16*)(ws + (4u << 20));               // 4 MB
    u16* vtb       = (u16*)(ws + (8u << 20));               // 4 MB
    u16* attnb     = (u16*)(ws + (12u << 20));              // 4 MB
    u16* relk_pad  = (u16*)(ws + (16u << 20));              // 256 KB
    u16* relvt_pad = (u16*)(ws + (16u << 20) + 262144);     // 256 KB
    u16* wfcb      = (u16*)(ws + (16u << 20) + 524288);     // 512 KB

    proj_mfma_kernel<<<dim3(BB * HH, LL / 64), 256, 0, stream>>>(
        query, key, value, Wq, bq, Wk, bk, Wv, bv, qb, kb, vtb);
    prep_kernel<<<1024, 256, 0, stream>>>(relk, relv, Wfc, relk_pad, relvt_pad, wfcb);
    attn_mfma_kernel<<<dim3(BB * HH, LL / 32), 256, 0, stream>>>(
        qb, kb, vtb, mask, relk_pad, relvt_pad, attnb);
    fc_mfma_kernel<<<dim3(BB * LL / 128, EE / 128), 256, 0, stream>>>(attnb, wfcb, bfc, out);
}

// Round 14
// 108.185 us; speedup vs baseline: 1.4143x; 1.4143x over previous
//
#include <hip/hip_runtime.h>
#include <math.h>

#define BB 4
#define LL 1024
#define EE 512
#define HH 8
#define DD 64
#define MAXREL 512

typedef unsigned short u16;
typedef __attribute__((ext_vector_type(8))) short bf16x8;
typedef __attribute__((ext_vector_type(4))) float f32x4;

__device__ __forceinline__ u16 f2bf(float f) {
    unsigned int u = __float_as_uint(f);
    unsigned int r = (u + 0x7FFFu + ((u >> 16) & 1u)) >> 16;
    return (u16)r;
}
__device__ __forceinline__ bf16x8 ldf8_bf(const float* p) {
    const float4 a = *(const float4*)(p);
    const float4 b = *(const float4*)(p + 4);
    bf16x8 r;
    r[0] = (short)f2bf(a.x); r[1] = (short)f2bf(a.y);
    r[2] = (short)f2bf(a.z); r[3] = (short)f2bf(a.w);
    r[4] = (short)f2bf(b.x); r[5] = (short)f2bf(b.y);
    r[6] = (short)f2bf(b.z); r[7] = (short)f2bf(b.w);
    return r;
}

#define MF(A, B, C) __builtin_amdgcn_mfma_f32_16x16x32_bf16((A), (B), (C), 0, 0, 0)
// exp(x/8) = exp2(x * log2(e)/8)
#define EXPSC 0.1803368801111244f

// ---------------- projection via MFMA ----------------
__global__ __launch_bounds__(256) void proj_mfma_kernel(
    const float* __restrict__ q_in, const float* __restrict__ k_in, const float* __restrict__ v_in,
    const float* __restrict__ Wq, const float* __restrict__ bq,
    const float* __restrict__ Wk, const float* __restrict__ bk,
    const float* __restrict__ Wv, const float* __restrict__ bv,
    u16* __restrict__ qb, u16* __restrict__ kb, u16* __restrict__ vtb)
{
    int bh = blockIdx.x; int b = bh >> 3; int h = bh & 7;
    int l0 = blockIdx.y * 64;
    int t = threadIdx.x; int w = t >> 6; int lane = t & 63;
    int lg = lane >> 4, lc = lane & 15;
    int lt = l0 + w * 16;

    bf16x8 wq[4][2], wk[4][2], wv[4][2];
    #pragma unroll
    for (int dt = 0; dt < 4; ++dt)
        #pragma unroll
        for (int kc = 0; kc < 2; ++kc) {
            int d = dt * 16 + lc, ko = kc * 32 + lg * 8;
            wq[dt][kc] = ldf8_bf(Wq + d * DD + ko);
            wk[dt][kc] = ldf8_bf(Wk + d * DD + ko);
            wv[dt][kc] = ldf8_bf(Wv + d * DD + ko);
        }
    size_t xrow = ((size_t)b * LL + lt + lc) * EE + h * DD;
    bf16x8 xq[2], xk[2], xv[2];
    #pragma unroll
    for (int kc = 0; kc < 2; ++kc) {
        int ko = kc * 32 + lg * 8;
        xq[kc] = ldf8_bf(q_in + xrow + ko);
        xk[kc] = ldf8_bf(k_in + xrow + ko);
        xv[kc] = ldf8_bf(v_in + xrow + ko);
    }

    f32x4 aq[4] = {}, ak[4] = {}, av[4] = {};
    #pragma unroll
    for (int dt = 0; dt < 4; ++dt) {
        aq[dt] = MF(wq[dt][0], xq[0], aq[dt]);
        aq[dt] = MF(wq[dt][1], xq[1], aq[dt]);
        ak[dt] = MF(wk[dt][0], xk[0], ak[dt]);
        ak[dt] = MF(wk[dt][1], xk[1], ak[dt]);
        av[dt] = MF(xv[0], wv[dt][0], av[dt]);
        av[dt] = MF(xv[1], wv[dt][1], av[dt]);
    }

    #pragma unroll
    for (int dt = 0; dt < 4; ++dt) {
        u16 tq[4], tk[4], tv[4];
        #pragma unroll
        for (int r = 0; r < 4; ++r) {
            int d = dt * 16 + lg * 4 + r;
            tq[r] = f2bf(aq[dt][r] + bq[d]);
            tk[r] = f2bf(ak[dt][r] + bk[d]);
            tv[r] = f2bf(av[dt][r] + bv[dt * 16 + lc]);
        }
        size_t o = ((size_t)bh * LL + lt + lc) * DD + dt * 16 + lg * 4;
        *(uint2*)&qb[o] = *(uint2*)tq;
        *(uint2*)&kb[o] = *(uint2*)tk;
        size_t ov = ((size_t)bh * DD + dt * 16 + lc) * LL + lt + lg * 4;
        *(uint2*)&vtb[ov] = *(uint2*)tv;
    }
}

// ---------------- prep: padded bf16 rel tables + bf16 Wfc ----------------
__global__ __launch_bounds__(256) void prep_kernel(
    const float* __restrict__ relk, const float* __restrict__ relv, const float* __restrict__ Wfc,
    u16* __restrict__ relk_pad, u16* __restrict__ relvt_pad, u16* __restrict__ wfcb)
{
    int idx = blockIdx.x * 256 + threadIdx.x;   // 1024 blocks -> 262144
    if (idx < 2048 * DD) {
        int r = idx >> 6, d = idx & 63;
        int j = r - 512; j = j < 0 ? 0 : (j > 2 * MAXREL ? 2 * MAXREL : j);
        relk_pad[idx] = f2bf(relk[j * DD + d]);
        int dd = idx >> 11, c = idx & 2047;
        int j2 = c - 512; j2 = j2 < 0 ? 0 : (j2 > 2 * MAXREL ? 2 * MAXREL : j2);
        relvt_pad[idx] = f2bf(relv[j2 * DD + dd]);
    }
    if (idx < EE * EE) wfcb[idx] = f2bf(Wfc[idx]);
}

// ---------------- fused attention: softmax-behind pipeline, single-K buffer ----------------
// grid (B*H, L/32), block 256 (4 waves). 2 barriers/chunk. Wave-local P.
// Iter c: scores+softmax of chunk c+1 (Ks holds K(c+1); K(c+2) written after barrier), PV of chunk c.
__global__ __launch_bounds__(256) void attn_mfma_kernel(
    const u16* __restrict__ qb, const u16* __restrict__ kb, const u16* __restrict__ vtb,
    const int* __restrict__ mask,
    const u16* __restrict__ relk_pad, const u16* __restrict__ relvt_pad,
    u16* __restrict__ attn_out)
{
    __shared__ __align__(16) char smem[48384];
    u16* Ks   = (u16*)(smem);             // [64][72]   9216 (single buffer)
    u16* Vts  = (u16*)(smem + 9216);      // [64][72]   9216
    u16* RVts = (u16*)(smem + 18432);     // [64][120] 15360
    float* lred = (float*)(smem + 48128); // [64]
    float* obuf = (float*)smem;           // epilogue reuse [32][68]

    int bh = blockIdx.x, b = bh >> 3, h = bh & 7;
    int q0 = blockIdx.y * 32;
    int t = threadIdx.x, lane = t & 63, w = t >> 6;
    int rw = w & 1, cw = w >> 1;
    int rbase = rw * 16, c0a = cw * 32;
    int lg = lane >> 4, lc = lane & 15;
    int ub = c0a - rbase + 16;            // window base (0,16,32,48)
    size_t bhL = (size_t)bh * LL;
    const u16* kb_bh = kb + bhL * DD;
    const u16* vt_bh = vtb + (size_t)bh * DD * LL;
    const int* mk_b = mask + b * LL;
    u16* Pw  = (u16*)(smem + 33792) + w * 640;   // [16][40] per wave
    u16* Pqw = (u16*)(smem + 38912) + w * 1152;  // [16][72] per wave

    // staging index precompute
    int sr0 = t >> 3, ss0 = (t & 7) * 8;
    int sr1 = sr0 + 32;
    int rv_row = t >> 2, rv_q = (t & 3) * 24;
    const u16* rvg = relvt_pad + (size_t)rv_row * 2048 + rv_q;
    u16* rvl = RVts + rv_row * 120 + rv_q;
    const u16* rk_base = relk_pad + (size_t)(ub + lc) * DD + lg * 8;

    const u16* qrow = qb + (bhL + q0 + rbase + lc) * DD;
    bf16x8 qf0 = *(const bf16x8*)&qrow[lg * 8];
    bf16x8 qf1 = *(const bf16x8*)&qrow[32 + lg * 8];

    f32x4 s0, s1, g0, g1, g2;
    bf16x8 rk0, rk1, rk2, rk3, rk4, rk5;
    f32x4 oacc[4] = {};
    float lacc[4] = {0.f, 0.f, 0.f, 0.f};
    int delta0 = lc - lg * 4;

#define LOAD_RK(SB) do { \
    const u16* rkp_ = rk_base + (size_t)(SB) * DD; \
    rk0 = *(const bf16x8*)&rkp_[0]; \
    rk1 = *(const bf16x8*)&rkp_[32]; \
    rk2 = *(const bf16x8*)&rkp_[16 * DD]; \
    rk3 = *(const bf16x8*)&rkp_[16 * DD + 32]; \
    rk4 = *(const bf16x8*)&rkp_[32 * DD]; \
    rk5 = *(const bf16x8*)&rkp_[32 * DD + 32]; \
} while (0)

#define DO_SCORES() do { \
    const u16* kp0_ = Ks + (c0a + lc) * 72; \
    const u16* kp1_ = Ks + (c0a + 16 + lc) * 72; \
    s0 = (f32x4){0.f,0.f,0.f,0.f}; s1 = s0; g0 = s0; g1 = s0; g2 = s0; \
    __builtin_amdgcn_s_setprio(1); \
    s0 = MF(qf0, *(const bf16x8*)&kp0_[lg * 8], s0); \
    s0 = MF(qf1, *(const bf16x8*)&kp0_[32 + lg * 8], s0); \
    s1 = MF(qf0, *(const bf16x8*)&kp1_[lg * 8], s1); \
    s1 = MF(qf1, *(const bf16x8*)&kp1_[32 + lg * 8], s1); \
    g0 = MF(qf0, rk0, g0); g0 = MF(qf1, rk1, g0); \
    g1 = MF(qf0, rk2, g1); g1 = MF(qf1, rk3, g1); \
    g2 = MF(qf0, rk4, g2); g2 = MF(qf1, rk5, g2); \
    __builtin_amdgcn_s_setprio(0); \
} while (0)

#define DO_SOFTMAX(MB0, MB1) do { \
    _Pragma("unroll") \
    for (int r = 0; r < 4; ++r) { \
        int d_ = delta0 - r; \
        int src_ = (lane & 48) | (d_ & 15); \
        float a0_ = __shfl(g0[r], src_, 64); \
        float a1_ = __shfl(g1[r], src_, 64); \
        float a2_ = __shfl(g2[r], src_, 64); \
        float gv0_ = (d_ >= 0) ? a1_ : a0_; \
        float gv1_ = (d_ >= 0) ? a2_ : a1_; \
        float p0_ = exp2f((s0[r] + (MB0) + gv0_) * EXPSC); \
        float p1_ = exp2f((s1[r] + (MB1) + gv1_) * EXPSC); \
        unsigned pk_; \
        asm("v_cvt_pk_bf16_f32 %0, %1, %2" : "=v"(pk_) : "v"(p0_), "v"(p1_)); \
        u16 pb0_ = (u16)pk_, pb1_ = (u16)(pk_ >> 16); \
        lacc[r] += p0_ + p1_; \
        int row_ = lg * 4 + r; \
        Pw[row_ * 40 + lc] = pb0_; \
        Pw[row_ * 40 + 16 + lc] = pb1_; \
        Pqw[row_ * 72 + lc - row_ + 16] = pb0_; \
        Pqw[row_ * 72 + 32 + lc - row_] = pb1_; \
    } \
} while (0)

    // ---- prolog ----
    #pragma unroll
    for (int i = 0; i < 3; ++i) {
        int u = lane + i * 64;
        if (u < 144) *(uint4*)&Pqw[u * 8] = make_uint4(0, 0, 0, 0);
    }
    if (t < 192) {
        int row = t / 3, j = t - row * 3;
        *(uint4*)&RVts[row * 120 + 96 + j * 8] = make_uint4(0, 0, 0, 0);
    }
    int sb0 = 992 - q0;
    *(uint4*)&Ks[sr0 * 72 + ss0] = *(const uint4*)&kb_bh[(size_t)sr0 * DD + ss0];
    *(uint4*)&Ks[sr1 * 72 + ss0] = *(const uint4*)&kb_bh[(size_t)sr1 * DD + ss0];
    *(uint4*)&Vts[sr0 * 72 + ss0] = *(const uint4*)&vt_bh[(size_t)sr0 * LL + ss0];
    *(uint4*)&Vts[sr1 * 72 + ss0] = *(const uint4*)&vt_bh[(size_t)sr1 * LL + ss0];
    *(uint4*)&rvl[0]  = *(const uint4*)&rvg[sb0];
    *(uint4*)&rvl[8]  = *(const uint4*)&rvg[sb0 + 8];
    *(uint4*)&rvl[16] = *(const uint4*)&rvg[sb0 + 16];
    LOAD_RK(sb0);
    float mbp0 = (mk_b[c0a + lc] != 0) ? 0.f : -1e20f;
    float mbp1 = (mk_b[c0a + 16 + lc] != 0) ? 0.f : -1e20f;
    __syncthreads();
    DO_SCORES();                          // chunk 0 (Ks = K(0))
    LOAD_RK(sb0 + 64);                    // rel-K(1)
    DO_SOFTMAX(mbp0, mbp1);               // P(0)
    {
        uint4 k1a = *(const uint4*)&kb_bh[(size_t)(64 + sr0) * DD + ss0];
        uint4 k1b = *(const uint4*)&kb_bh[(size_t)(64 + sr1) * DD + ss0];
        __syncthreads();                  // all done reading K(0)
        *(uint4*)&Ks[sr0 * 72 + ss0] = k1a;
        *(uint4*)&Ks[sr1 * 72 + ss0] = k1b;
        __syncthreads();                  // Ks = K(1)
    }

    // ---- main loop: iter c does scores/softmax(c+1) + PV(c) ----
    #pragma unroll 1
    for (int c = 0; c < 16; ++c) {
        int k0 = c * 64;
        int sb_ = k0 - q0 + 992;
        uint4 rK0, rK1, rV0, rV1, rRV0, rRV1, rRV2;
        float mbn0 = 0.f, mbn1 = 0.f;
        if (c < 14) {
            rK0 = *(const uint4*)&kb_bh[(size_t)(k0 + 128 + sr0) * DD + ss0];
            rK1 = *(const uint4*)&kb_bh[(size_t)(k0 + 128 + sr1) * DD + ss0];
        }
        if (c < 15) {
            int k0n = k0 + 64;
            int sbn = sb_ + 64;
            rV0  = *(const uint4*)&vt_bh[(size_t)sr0 * LL + k0n + ss0];
            rV1  = *(const uint4*)&vt_bh[(size_t)sr1 * LL + k0n + ss0];
            rRV0 = *(const uint4*)&rvg[sbn];
            rRV1 = *(const uint4*)&rvg[sbn + 8];
            rRV2 = *(const uint4*)&rvg[sbn + 16];
            mbn0 = (mk_b[k0n + c0a + lc] != 0) ? 0.f : -1e20f;
            mbn1 = (mk_b[k0n + c0a + 16 + lc] != 0) ? 0.f : -1e20f;
        }

        // P(c) fragments (written last iteration / prolog; wave-local)
        bf16x8 pa  = *(const bf16x8*)&Pw[lc * 40 + lg * 8];
        bf16x8 pq0 = *(const bf16x8*)&Pqw[lc * 72 + lg * 8];
        bf16x8 pq1 = *(const bf16x8*)&Pqw[lc * 72 + 32 + lg * 8];

        if (c < 15) {
            DO_SCORES();                       // chunk c+1 (Ks = K(c+1))
            if (c < 14) LOAD_RK(sb_ + 128);    // rel-K(c+2)
        }

        // PV(c) — independent of scores(c+1)
        __builtin_amdgcn_s_setprio(1);
        #pragma unroll
        for (int dt = 0; dt < 4; ++dt) {
            const u16* vp = &Vts[(dt * 16 + lc) * 72 + c0a];
            const u16* rp = &RVts[(dt * 16 + lc) * 120 + ub];
            oacc[dt] = MF(pa,  *(const bf16x8*)&vp[lg * 8], oacc[dt]);
            oacc[dt] = MF(pq0, *(const bf16x8*)&rp[lg * 8], oacc[dt]);
            oacc[dt] = MF(pq1, *(const bf16x8*)&rp[32 + lg * 8], oacc[dt]);
        }
        __builtin_amdgcn_s_setprio(0);

        if (c < 15) {
            DO_SOFTMAX(mbn0, mbn1);            // P(c+1), overlaps PV drain
            __syncthreads();                   // all waves done reading chunk c tiles
            if (c < 14) {
                *(uint4*)&Ks[sr0 * 72 + ss0] = rK0;   // Ks <- K(c+2)
                *(uint4*)&Ks[sr1 * 72 + ss0] = rK1;
            }
            *(uint4*)&Vts[sr0 * 72 + ss0] = rV0;
            *(uint4*)&Vts[sr1 * 72 + ss0] = rV1;
            *(uint4*)&rvl[0]  = rRV0;
            *(uint4*)&rvl[8]  = rRV1;
            *(uint4*)&rvl[16] = rRV2;
            __syncthreads();                   // chunk c+1 tiles visible
        }
    }
#undef LOAD_RK
#undef DO_SCORES
#undef DO_SOFTMAX

    // ---- epilogue: row-sum + cw-pair combine ----
    #pragma unroll
    for (int m2 = 1; m2 <= 8; m2 <<= 1) {
        #pragma unroll
        for (int r = 0; r < 4; ++r) lacc[r] += __shfl_xor(lacc[r], m2);
    }
    __syncthreads();
    if (lc == 0) {
        #pragma unroll
        for (int r = 0; r < 4; ++r) lred[cw * 32 + rbase + lg * 4 + r] = lacc[r];
    }
    __syncthreads();
    if (cw == 1) {
        #pragma unroll
        for (int dt = 0; dt < 4; ++dt)
            #pragma unroll
            for (int r = 0; r < 4; ++r)
                obuf[(rbase + lg * 4 + r) * 68 + dt * 16 + lc] = oacc[dt][r];
    }
    __syncthreads();
    if (cw == 0) {
        float inv[4];
        #pragma unroll
        for (int r = 0; r < 4; ++r) {
            int row = rbase + lg * 4 + r;
            inv[r] = 1.0f / (lred[row] + lred[32 + row]);
        }
        #pragma unroll
        for (int dt = 0; dt < 4; ++dt) {
            #pragma unroll
            for (int r = 0; r < 4; ++r) {
                int row = rbase + lg * 4 + r;
                float v = (oacc[dt][r] + obuf[row * 68 + dt * 16 + lc]) * inv[r];
                attn_out[((size_t)b * LL + q0 + row) * EE + h * DD + dt * 16 + lc] = f2bf(v);
            }
        }
    }
}

// ---------------- final FC via MFMA: out = X @ Wfc.T + bfc ----------------
__global__ __launch_bounds__(256) void fc_mfma_kernel(
    const u16* __restrict__ Xb, const u16* __restrict__ Wb,
    const float* __restrict__ bfc, float* __restrict__ out)
{
    __shared__ u16 As[128][72];
    __shared__ u16 Bs[128][72];
    int m0 = blockIdx.x * 128, n0 = blockIdx.y * 128;
    int t = threadIdx.x, lane = t & 63, w = t >> 6;
    int rw = w & 1, cw = w >> 1;
    int lg = lane >> 4, lc = lane & 15;
    f32x4 acc[4][4] = {};

    for (int kt = 0; kt < EE; kt += 64) {
        __syncthreads();
        #pragma unroll
        for (int i = 0; i < 4; ++i) {
            int unit = i * 256 + t;
            int row = unit >> 3, s = unit & 7;
            *(uint4*)&As[row][s * 8] = *(const uint4*)&Xb[(size_t)(m0 + row) * EE + kt + s * 8];
            *(uint4*)&Bs[row][s * 8] = *(const uint4*)&Wb[(size_t)(n0 + row) * EE + kt + s * 8];
        }
        __syncthreads();
        #pragma unroll
        for (int kc = 0; kc < 2; ++kc) {
            bf16x8 af[4], bf[4];
            #pragma unroll
            for (int i = 0; i < 4; ++i) {
                af[i] = *(const bf16x8*)&As[rw * 64 + i * 16 + lc][kc * 32 + lg * 8];
                bf[i] = *(const bf16x8*)&Bs[cw * 64 + i * 16 + lc][kc * 32 + lg * 8];
            }
            #pragma unroll
            for (int mi = 0; mi < 4; ++mi)
                #pragma unroll
                for (int ni = 0; ni < 4; ++ni)
                    acc[mi][ni] = MF(af[mi], bf[ni], acc[mi][ni]);
        }
    }
    #pragma unroll
    for (int mi = 0; mi < 4; ++mi) {
        #pragma unroll
        for (int ni = 0; ni < 4; ++ni) {
            int n = n0 + cw * 64 + ni * 16 + lc;
            float bias = bfc[n];
            #pragma unroll
            for (int r = 0; r < 4; ++r) {
                int m = m0 + rw * 64 + mi * 16 + lg * 4 + r;
                out[(size_t)m * EE + n] = acc[mi][ni][r] + bias;
            }
        }
    }
}

extern "C" void kernel_launch(void* const* d_in, const int* in_sizes, int n_in,
                              void* d_out, int out_size, void* d_ws, size_t ws_size,
                              hipStream_t stream) {
    const float* query = (const float*)d_in[0];
    const float* key   = (const float*)d_in[1];
    const float* value = (const float*)d_in[2];
    const int*   mask  = (const int*)d_in[3];
    const float* Wq  = (const float*)d_in[4];
    const float* bq  = (const float*)d_in[5];
    const float* Wk  = (const float*)d_in[6];
    const float* bk  = (const float*)d_in[7];
    const float* Wv  = (const float*)d_in[8];
    const float* bv  = (const float*)d_in[9];
    const float* Wfc = (const float*)d_in[10];
    const float* bfc = (const float*)d_in[11];
    const float* relk = (const float*)d_in[12];
    const float* relv = (const float*)d_in[13];
    float* out = (float*)d_out;

    char* ws = (char*)d_ws;
    u16* qb        = (u16*)(ws);                            // 4 MB
    u16* kb        = (u16*)(ws + (4u << 20));               // 4 MB
    u16* vtb       = (u16*)(ws + (8u << 20));               // 4 MB
    u16* attnb     = (u16*)(ws + (12u << 20));              // 4 MB
    u16* relk_pad  = (u16*)(ws + (16u << 20));              // 256 KB
    u16* relvt_pad = (u16*)(ws + (16u << 20) + 262144);     // 256 KB
    u16* wfcb      = (u16*)(ws + (16u << 20) + 524288);     // 512 KB

    proj_mfma_kernel<<<dim3(BB * HH, LL / 64), 256, 0, stream>>>(
        query, key, value, Wq, bq, Wk, bk, Wv, bv, qb, kb, vtb);
    prep_kernel<<<1024, 256, 0, stream>>>(relk, relv, Wfc, relk_pad, relvt_pad, wfcb);
    attn_mfma_kernel<<<dim3(BB * HH, LL / 32), 256, 0, stream>>>(
        qb, kb, vtb, mask, relk_pad, relvt_pad, attnb);
    fc_mfma_kernel<<<dim3(BB * LL / 128, EE / 128), 256, 0, stream>>>(attnb, wfcb, bfc, out);
}

// Round 15
// 107.250 us; speedup vs baseline: 1.4266x; 1.0087x over previous
//
#include <hip/hip_runtime.h>
#include <math.h>

#define BB 4
#define LL 1024
#define EE 512
#define HH 8
#define DD 64
#define MAXREL 512

typedef unsigned short u16;
typedef __attribute__((ext_vector_type(8))) short bf16x8;
typedef __attribute__((ext_vector_type(4))) float f32x4;
typedef __attribute__((ext_vector_type(16))) float f32x16;

__device__ __forceinline__ u16 f2bf(float f) {
    unsigned int u = __float_as_uint(f);
    unsigned int r = (u + 0x7FFFu + ((u >> 16) & 1u)) >> 16;
    return (u16)r;
}
__device__ __forceinline__ bf16x8 ldf8_bf(const float* p) {
    const float4 a = *(const float4*)(p);
    const float4 b = *(const float4*)(p + 4);
    bf16x8 r;
    r[0] = (short)f2bf(a.x); r[1] = (short)f2bf(a.y);
    r[2] = (short)f2bf(a.z); r[3] = (short)f2bf(a.w);
    r[4] = (short)f2bf(b.x); r[5] = (short)f2bf(b.y);
    r[6] = (short)f2bf(b.z); r[7] = (short)f2bf(b.w);
    return r;
}

#define MF(A, B, C)   __builtin_amdgcn_mfma_f32_16x16x32_bf16((A), (B), (C), 0, 0, 0)
#define MF32(A, B, C) __builtin_amdgcn_mfma_f32_32x32x16_bf16((A), (B), (C), 0, 0, 0)
// exp(x/8) = exp2(x * log2(e)/8)
#define EXPSC 0.1803368801111244f

// ---------------- projection via MFMA ----------------
__global__ __launch_bounds__(256) void proj_mfma_kernel(
    const float* __restrict__ q_in, const float* __restrict__ k_in, const float* __restrict__ v_in,
    const float* __restrict__ Wq, const float* __restrict__ bq,
    const float* __restrict__ Wk, const float* __restrict__ bk,
    const float* __restrict__ Wv, const float* __restrict__ bv,
    u16* __restrict__ qb, u16* __restrict__ kb, u16* __restrict__ vtb)
{
    int bh = blockIdx.x; int b = bh >> 3; int h = bh & 7;
    int l0 = blockIdx.y * 64;
    int t = threadIdx.x; int w = t >> 6; int lane = t & 63;
    int lg = lane >> 4, lc = lane & 15;
    int lt = l0 + w * 16;

    bf16x8 wq[4][2], wk[4][2], wv[4][2];
    #pragma unroll
    for (int dt = 0; dt < 4; ++dt)
        #pragma unroll
        for (int kc = 0; kc < 2; ++kc) {
            int d = dt * 16 + lc, ko = kc * 32 + lg * 8;
            wq[dt][kc] = ldf8_bf(Wq + d * DD + ko);
            wk[dt][kc] = ldf8_bf(Wk + d * DD + ko);
            wv[dt][kc] = ldf8_bf(Wv + d * DD + ko);
        }
    size_t xrow = ((size_t)b * LL + lt + lc) * EE + h * DD;
    bf16x8 xq[2], xk[2], xv[2];
    #pragma unroll
    for (int kc = 0; kc < 2; ++kc) {
        int ko = kc * 32 + lg * 8;
        xq[kc] = ldf8_bf(q_in + xrow + ko);
        xk[kc] = ldf8_bf(k_in + xrow + ko);
        xv[kc] = ldf8_bf(v_in + xrow + ko);
    }

    f32x4 aq[4] = {}, ak[4] = {}, av[4] = {};
    #pragma unroll
    for (int dt = 0; dt < 4; ++dt) {
        aq[dt] = MF(wq[dt][0], xq[0], aq[dt]);
        aq[dt] = MF(wq[dt][1], xq[1], aq[dt]);
        ak[dt] = MF(wk[dt][0], xk[0], ak[dt]);
        ak[dt] = MF(wk[dt][1], xk[1], ak[dt]);
        av[dt] = MF(xv[0], wv[dt][0], av[dt]);
        av[dt] = MF(xv[1], wv[dt][1], av[dt]);
    }

    #pragma unroll
    for (int dt = 0; dt < 4; ++dt) {
        u16 tq[4], tk[4], tv[4];
        #pragma unroll
        for (int r = 0; r < 4; ++r) {
            int d = dt * 16 + lg * 4 + r;
            tq[r] = f2bf(aq[dt][r] + bq[d]);
            tk[r] = f2bf(ak[dt][r] + bk[d]);
            tv[r] = f2bf(av[dt][r] + bv[dt * 16 + lc]);
        }
        size_t o = ((size_t)bh * LL + lt + lc) * DD + dt * 16 + lg * 4;
        *(uint2*)&qb[o] = *(uint2*)tq;
        *(uint2*)&kb[o] = *(uint2*)tk;
        size_t ov = ((size_t)bh * DD + dt * 16 + lc) * LL + lt + lg * 4;
        *(uint2*)&vtb[ov] = *(uint2*)tv;
    }
}

// ---------------- prep: padded bf16 rel tables + bf16 Wfc ----------------
// relk_pad [2048][64]; relvt2 [64][3072] (col c -> relv[clamp(c-512,0,1024)][d]); wfcb.
__global__ __launch_bounds__(256) void prep_kernel(
    const float* __restrict__ relk, const float* __restrict__ relv, const float* __restrict__ Wfc,
    u16* __restrict__ relk_pad, u16* __restrict__ relvt2, u16* __restrict__ wfcb)
{
    int idx = blockIdx.x * 256 + threadIdx.x;   // 1024 blocks -> 262144
    if (idx < 2048 * DD) {
        int r = idx >> 6, d = idx & 63;
        int j = r - 512; j = j < 0 ? 0 : (j > 2 * MAXREL ? 2 * MAXREL : j);
        relk_pad[idx] = f2bf(relk[j * DD + d]);
    }
    if (idx < DD * 3072) {
        int d = idx / 3072;
        int c = idx - d * 3072;
        int j = c - 512; j = j < 0 ? 0 : (j > 2 * MAXREL ? 2 * MAXREL : j);
        relvt2[idx] = f2bf(relv[j * DD + d]);
    }
    if (idx < EE * EE) wfcb[idx] = f2bf(Wfc[idx]);
}

// ---------------- fused attention: softmax-behind pipeline, 32x32 PV, shared P ----------------
// grid (B*H, L/32), block 256 (4 waves). 2 barriers/chunk.
// Softmax roles: wave (rw,cw) = q-rows rw*16..+16, k-cols cw*32..+32 (16x16 MFMA, unchanged).
// PV roles: wave (kh=rw, dh=cw) = k-half kh, d-slice dh*32 (32x32 MFMA, block-shared P).
// P fragments are read in the B1..B2 stage window (race-free by barrier fencing).
__global__ __launch_bounds__(256) void attn_mfma_kernel(
    const u16* __restrict__ qb, const u16* __restrict__ kb, const u16* __restrict__ vtb,
    const int* __restrict__ mask,
    const u16* __restrict__ relk_pad, const u16* __restrict__ relvt2,
    u16* __restrict__ attn_out)
{
    __shared__ __align__(16) char smem[45312];
    u16* Ks   = (u16*)(smem);             // [64][72]   9216 (single buffer)
    u16* Vts  = (u16*)(smem + 9216);      // [64][72]   9216
    u16* RVts = (u16*)(smem + 18432);     // [64][120] 15360 (cols 0..95 staged)
    u16* Ps   = (u16*)(smem + 33792);     // [32][72]   4608 (block-shared P)
    u16* Pqs  = (u16*)(smem + 38400);     // [32][104]  6656 (block-shared P', diag-shifted)
    float* lred = (float*)(smem + 45056); // [64]
    float* obuf = (float*)smem;           // epilogue reuse [32][68] f32 (8704 B, over Ks)

    int bh = blockIdx.x, b = bh >> 3, h = bh & 7;
    int q0 = blockIdx.y * 32;
    int t = threadIdx.x, lane = t & 63, w = t >> 6;
    int rw = w & 1, cw = w >> 1;
    int rbase = rw * 16, c0a = cw * 32;
    int lg = lane >> 4, lc = lane & 15;
    int ub = c0a - rbase + 16;            // G gather window base
    int m_ = lane & 31, h8 = (lane >> 5) * 8, hh = (lane >> 5) * 4;
    size_t bhL = (size_t)bh * LL;
    const u16* kb_bh = kb + bhL * DD;
    const u16* vt_bh = vtb + (size_t)bh * DD * LL;
    const int* mk_b = mask + b * LL;

    // staging index precompute
    int sr0 = t >> 3, ss0 = (t & 7) * 8;
    int sr1 = sr0 + 32;
    int rv_row = t >> 2, rv_q = (t & 3) * 24;
    const u16* rvg = relvt2 + (size_t)rv_row * 3072 + rv_q;
    u16* rvl = RVts + rv_row * 120 + rv_q;
    const u16* rk_base = relk_pad + (size_t)(ub + lc) * DD + lg * 8;

    const u16* qrow = qb + (bhL + q0 + rbase + lc) * DD;
    bf16x8 qf0 = *(const bf16x8*)&qrow[lg * 8];
    bf16x8 qf1 = *(const bf16x8*)&qrow[32 + lg * 8];

    f32x4 s0, s1, g0, g1, g2;
    bf16x8 rk0, rk1, rk2, rk3, rk4, rk5;
    bf16x8 pa0, pa1, pr0, pr1, pr2;       // preloaded P/P' fragments
    f32x16 oacc = {};
    float lacc[4] = {0.f, 0.f, 0.f, 0.f};
    int delta0 = lc - lg * 4;

#define LOAD_RK(SB) do { \
    const u16* rkp_ = rk_base + (size_t)(SB) * DD; \
    rk0 = *(const bf16x8*)&rkp_[0]; \
    rk1 = *(const bf16x8*)&rkp_[32]; \
    rk2 = *(const bf16x8*)&rkp_[16 * DD]; \
    rk3 = *(const bf16x8*)&rkp_[16 * DD + 32]; \
    rk4 = *(const bf16x8*)&rkp_[32 * DD]; \
    rk5 = *(const bf16x8*)&rkp_[32 * DD + 32]; \
} while (0)

#define DO_SCORES() do { \
    const u16* kp0_ = Ks + (c0a + lc) * 72; \
    const u16* kp1_ = Ks + (c0a + 16 + lc) * 72; \
    s0 = (f32x4){0.f,0.f,0.f,0.f}; s1 = s0; g0 = s0; g1 = s0; g2 = s0; \
    __builtin_amdgcn_s_setprio(1); \
    s0 = MF(qf0, *(const bf16x8*)&kp0_[lg * 8], s0); \
    s0 = MF(qf1, *(const bf16x8*)&kp0_[32 + lg * 8], s0); \
    s1 = MF(qf0, *(const bf16x8*)&kp1_[lg * 8], s1); \
    s1 = MF(qf1, *(const bf16x8*)&kp1_[32 + lg * 8], s1); \
    g0 = MF(qf0, rk0, g0); g0 = MF(qf1, rk1, g0); \
    g1 = MF(qf0, rk2, g1); g1 = MF(qf1, rk3, g1); \
    g2 = MF(qf0, rk4, g2); g2 = MF(qf1, rk5, g2); \
    __builtin_amdgcn_s_setprio(0); \
} while (0)

#define DO_SOFTMAX(MB0, MB1) do { \
    _Pragma("unroll") \
    for (int r = 0; r < 4; ++r) { \
        int d_ = delta0 - r; \
        int src_ = (lane & 48) | (d_ & 15); \
        float a0_ = __shfl(g0[r], src_, 64); \
        float a1_ = __shfl(g1[r], src_, 64); \
        float a2_ = __shfl(g2[r], src_, 64); \
        float gv0_ = (d_ >= 0) ? a1_ : a0_; \
        float gv1_ = (d_ >= 0) ? a2_ : a1_; \
        float p0_ = exp2f((s0[r] + (MB0) + gv0_) * EXPSC); \
        float p1_ = exp2f((s1[r] + (MB1) + gv1_) * EXPSC); \
        unsigned pk_; \
        asm("v_cvt_pk_bf16_f32 %0, %1, %2" : "=v"(pk_) : "v"(p0_), "v"(p1_)); \
        u16 pb0_ = (u16)pk_, pb1_ = (u16)(pk_ >> 16); \
        lacc[r] += p0_ + p1_; \
        int row_ = rbase + lg * 4 + r; \
        Ps[row_ * 72 + c0a + lc] = pb0_; \
        Ps[row_ * 72 + c0a + 16 + lc] = pb1_; \
        Pqs[row_ * 104 + c0a + lc - row_ + 32] = pb0_; \
        Pqs[row_ * 104 + c0a + 16 + lc - row_ + 32] = pb1_; \
    } \
} while (0)

#define READ_PFRAGS() do { \
    pa0 = *(const bf16x8*)&Ps[m_ * 72 + rw * 32 + h8]; \
    pa1 = *(const bf16x8*)&Ps[m_ * 72 + rw * 32 + 16 + h8]; \
    pr0 = *(const bf16x8*)&Pqs[m_ * 104 + rw * 48 + h8]; \
    pr1 = *(const bf16x8*)&Pqs[m_ * 104 + rw * 48 + 16 + h8]; \
    pr2 = *(const bf16x8*)&Pqs[m_ * 104 + rw * 48 + 32 + h8]; \
} while (0)

    // ---- prolog ----
    for (int i = t; i < 416; i += 256) ((uint4*)Pqs)[i] = make_uint4(0, 0, 0, 0);
    int sb0 = 992 - q0;
    *(uint4*)&Ks[sr0 * 72 + ss0] = *(const uint4*)&kb_bh[(size_t)sr0 * DD + ss0];
    *(uint4*)&Ks[sr1 * 72 + ss0] = *(const uint4*)&kb_bh[(size_t)sr1 * DD + ss0];
    *(uint4*)&Vts[sr0 * 72 + ss0] = *(const uint4*)&vt_bh[(size_t)sr0 * LL + ss0];
    *(uint4*)&Vts[sr1 * 72 + ss0] = *(const uint4*)&vt_bh[(size_t)sr1 * LL + ss0];
    *(uint4*)&rvl[0]  = *(const uint4*)&rvg[sb0];
    *(uint4*)&rvl[8]  = *(const uint4*)&rvg[sb0 + 8];
    *(uint4*)&rvl[16] = *(const uint4*)&rvg[sb0 + 16];
    LOAD_RK(sb0);
    float mbp0 = (mk_b[c0a + lc] != 0) ? 0.f : -1e20f;
    float mbp1 = (mk_b[c0a + 16 + lc] != 0) ? 0.f : -1e20f;
    __syncthreads();
    DO_SCORES();                          // chunk 0 (Ks = K(0))
    LOAD_RK(sb0 + 64);                    // rel-K(1)
    DO_SOFTMAX(mbp0, mbp1);               // P(0)
    {
        uint4 k1a = *(const uint4*)&kb_bh[(size_t)(64 + sr0) * DD + ss0];
        uint4 k1b = *(const uint4*)&kb_bh[(size_t)(64 + sr1) * DD + ss0];
        __syncthreads();                  // P(0) complete; K(0) reads done
        *(uint4*)&Ks[sr0 * 72 + ss0] = k1a;
        *(uint4*)&Ks[sr1 * 72 + ss0] = k1b;
        READ_PFRAGS();                    // P(0) fragments
        __syncthreads();                  // Ks = K(1) visible
    }

    // ---- main loop: iter c does scores/softmax(c+1) + PV(c) ----
    #pragma unroll 1
    for (int c = 0; c < 16; ++c) {
        int k0 = c * 64;
        int sb_ = k0 - q0 + 992;
        uint4 rK0, rK1, rV0, rV1, rRV0, rRV1, rRV2;
        float mbn0 = 0.f, mbn1 = 0.f;
        if (c < 14) {
            rK0 = *(const uint4*)&kb_bh[(size_t)(k0 + 128 + sr0) * DD + ss0];
            rK1 = *(const uint4*)&kb_bh[(size_t)(k0 + 128 + sr1) * DD + ss0];
        }
        if (c < 15) {
            int k0n = k0 + 64;
            int sbn = sb_ + 64;
            rV0  = *(const uint4*)&vt_bh[(size_t)sr0 * LL + k0n + ss0];
            rV1  = *(const uint4*)&vt_bh[(size_t)sr1 * LL + k0n + ss0];
            rRV0 = *(const uint4*)&rvg[sbn];
            rRV1 = *(const uint4*)&rvg[sbn + 8];
            rRV2 = *(const uint4*)&rvg[sbn + 16];
            mbn0 = (mk_b[k0n + c0a + lc] != 0) ? 0.f : -1e20f;
            mbn1 = (mk_b[k0n + c0a + 16 + lc] != 0) ? 0.f : -1e20f;
        }

        if (c < 15) {
            DO_SCORES();                       // chunk c+1 (Ks = K(c+1))
            if (c < 14) LOAD_RK(sb_ + 128);    // rel-K(c+2)
        }

        // PV(c): 32x32 MFMA, block-shared P fragments (preloaded)
        __builtin_amdgcn_s_setprio(1);
        {
            const u16* vrow = &Vts[(cw * 32 + m_) * 72 + rw * 32];
            const u16* rrow = &RVts[(cw * 32 + m_) * 120 + rw * 48];
            oacc = MF32(pa0, *(const bf16x8*)&vrow[h8], oacc);
            oacc = MF32(pa1, *(const bf16x8*)&vrow[16 + h8], oacc);
            oacc = MF32(pr0, *(const bf16x8*)&rrow[h8], oacc);
            oacc = MF32(pr1, *(const bf16x8*)&rrow[16 + h8], oacc);
            oacc = MF32(pr2, *(const bf16x8*)&rrow[32 + h8], oacc);
        }
        __builtin_amdgcn_s_setprio(0);

        if (c < 15) {
            DO_SOFTMAX(mbn0, mbn1);            // P(c+1), overlaps PV drain
            __syncthreads();                   // B1: all tile reads + P(c+1) writes done
            if (c < 14) {
                *(uint4*)&Ks[sr0 * 72 + ss0] = rK0;   // Ks <- K(c+2)
                *(uint4*)&Ks[sr1 * 72 + ss0] = rK1;
            }
            *(uint4*)&Vts[sr0 * 72 + ss0] = rV0;
            *(uint4*)&Vts[sr1 * 72 + ss0] = rV1;
            *(uint4*)&rvl[0]  = rRV0;
            *(uint4*)&rvl[8]  = rRV1;
            *(uint4*)&rvl[16] = rRV2;
            READ_PFRAGS();                     // P(c+1) fragments (fenced by B2 from future writes)
            __syncthreads();                   // B2: chunk c+1 tiles visible
        }
    }
#undef LOAD_RK
#undef DO_SCORES
#undef DO_SOFTMAX
#undef READ_PFRAGS

    // ---- epilogue: row-sum + k-half combine ----
    #pragma unroll
    for (int m2 = 1; m2 <= 8; m2 <<= 1) {
        #pragma unroll
        for (int r = 0; r < 4; ++r) lacc[r] += __shfl_xor(lacc[r], m2);
    }
    __syncthreads();
    if (lc == 0) {
        #pragma unroll
        for (int r = 0; r < 4; ++r) lred[cw * 32 + rbase + lg * 4 + r] = lacc[r];
    }
    __syncthreads();
    if (rw == 1) {
        #pragma unroll
        for (int reg = 0; reg < 16; ++reg) {
            int row = (reg & 3) + 8 * (reg >> 2) + hh;
            obuf[row * 68 + cw * 32 + m_] = oacc[reg];
        }
    }
    __syncthreads();
    if (rw == 0) {
        #pragma unroll
        for (int reg = 0; reg < 16; ++reg) {
            int row = (reg & 3) + 8 * (reg >> 2) + hh;
            float v = (oacc[reg] + obuf[row * 68 + cw * 32 + m_]) / (lred[row] + lred[32 + row]);
            attn_out[((size_t)b * LL + q0 + row) * EE + h * DD + cw * 32 + m_] = f2bf(v);
        }
    }
}

// ---------------- final FC via MFMA: out = X @ Wfc.T + bfc ----------------
__global__ __launch_bounds__(256) void fc_mfma_kernel(
    const u16* __restrict__ Xb, const u16* __restrict__ Wb,
    const float* __restrict__ bfc, float* __restrict__ out)
{
    __shared__ u16 As[128][72];
    __shared__ u16 Bs[128][72];
    int m0 = blockIdx.x * 128, n0 = blockIdx.y * 128;
    int t = threadIdx.x, lane = t & 63, w = t >> 6;
    int rw = w & 1, cw = w >> 1;
    int lg = lane >> 4, lc = lane & 15;
    f32x4 acc[4][4] = {};

    for (int kt = 0; kt < EE; kt += 64) {
        __syncthreads();
        #pragma unroll
        for (int i = 0; i < 4; ++i) {
            int unit = i * 256 + t;
            int row = unit >> 3, s = unit & 7;
            *(uint4*)&As[row][s * 8] = *(const uint4*)&Xb[(size_t)(m0 + row) * EE + kt + s * 8];
            *(uint4*)&Bs[row][s * 8] = *(const uint4*)&Wb[(size_t)(n0 + row) * EE + kt + s * 8];
        }
        __syncthreads();
        #pragma unroll
        for (int kc = 0; kc < 2; ++kc) {
            bf16x8 af[4], bf[4];
            #pragma unroll
            for (int i = 0; i < 4; ++i) {
                af[i] = *(const bf16x8*)&As[rw * 64 + i * 16 + lc][kc * 32 + lg * 8];
                bf[i] = *(const bf16x8*)&Bs[cw * 64 + i * 16 + lc][kc * 32 + lg * 8];
            }
            #pragma unroll
            for (int mi = 0; mi < 4; ++mi)
                #pragma unroll
                for (int ni = 0; ni < 4; ++ni)
                    acc[mi][ni] = MF(af[mi], bf[ni], acc[mi][ni]);
        }
    }
    #pragma unroll
    for (int mi = 0; mi < 4; ++mi) {
        #pragma unroll
        for (int ni = 0; ni < 4; ++ni) {
            int n = n0 + cw * 64 + ni * 16 + lc;
            float bias = bfc[n];
            #pragma unroll
            for (int r = 0; r < 4; ++r) {
                int m = m0 + rw * 64 + mi * 16 + lg * 4 + r;
                out[(size_t)m * EE + n] = acc[mi][ni][r] + bias;
            }
        }
    }
}

extern "C" void kernel_launch(void* const* d_in, const int* in_sizes, int n_in,
                              void* d_out, int out_size, void* d_ws, size_t ws_size,
                              hipStream_t stream) {
    const float* query = (const float*)d_in[0];
    const float* key   = (const float*)d_in[1];
    const float* value = (const float*)d_in[2];
    const int*   mask  = (const int*)d_in[3];
    const float* Wq  = (const float*)d_in[4];
    const float* bq  = (const float*)d_in[5];
    const float* Wk  = (const float*)d_in[6];
    const float* bk  = (const float*)d_in[7];
    const float* Wv  = (const float*)d_in[8];
    const float* bv  = (const float*)d_in[9];
    const float* Wfc = (const float*)d_in[10];
    const float* bfc = (const float*)d_in[11];
    const float* relk = (const float*)d_in[12];
    const float* relv = (const float*)d_in[13];
    float* out = (float*)d_out;

    char* ws = (char*)d_ws;
    u16* qb        = (u16*)(ws);                            // 4 MB
    u16* kb        = (u16*)(ws + (4u << 20));               // 4 MB
    u16* vtb       = (u16*)(ws + (8u << 20));               // 4 MB
    u16* attnb     = (u16*)(ws + (12u << 20));              // 4 MB
    u16* relk_pad  = (u16*)(ws + (16u << 20));              // 256 KB
    u16* relvt2    = (u16*)(ws + (16u << 20) + 262144);     // 384 KB
    u16* wfcb      = (u16*)(ws + (16u << 20) + 655360);     // 512 KB

    proj_mfma_kernel<<<dim3(BB * HH, LL / 64), 256, 0, stream>>>(
        query, key, value, Wq, bq, Wk, bk, Wv, bv, qb, kb, vtb);
    prep_kernel<<<1024, 256, 0, stream>>>(relk, relv, Wfc, relk_pad, relvt2, wfcb);
    attn_mfma_kernel<<<dim3(BB * HH, LL / 32), 256, 0, stream>>>(
        qb, kb, vtb, mask, relk_pad, relvt2, attnb);
    fc_mfma_kernel<<<dim3(BB * LL / 128, EE / 128), 256, 0, stream>>>(attnb, wfcb, bfc, out);
}